// Round 8
// baseline (5845.000 us; speedup 1.0000x reference)
//
#include <hip/hip_runtime.h>
#include <stdint.h>
#include <stddef.h>

#define S_LEN 512
#define BATCH 256
#define NIN   64
#define HD    512
#define G4    2048   // 4*H

typedef _Float16 f16;
typedef _Float16 f16x8 __attribute__((ext_vector_type(8)));
typedef float    f32x4 __attribute__((ext_vector_type(4)));
typedef uint32_t u32x4 __attribute__((ext_vector_type(4)));

// ============================ prep kernels ============================
__global__ void k_f32_to_f16(const float* __restrict__ src, f16* __restrict__ dst, int n) {
  int i = blockIdx.x * 256 + threadIdx.x;
  if (i < n) dst[i] = (f16)src[i];
}

// x [B,S,I] fp32 -> xin [(s*256+b)*64+i] fp16  (seq-major rows for the proj GEMM)
__global__ void k_x_transpose(const float* __restrict__ x, f16* __restrict__ xin) {
  int idx = blockIdx.x * 256 + threadIdx.x;
  int i  = idx & 63;
  int sb = idx >> 6;
  int b  = sb & 255;
  int s  = sb >> 8;
  xin[idx] = (f16)x[((size_t)b * S_LEN + s) * NIN + i];
}

__global__ void k_zero_i32(uint32_t* p, int n) {
  int i = blockIdx.x * 256 + threadIdx.x;
  if (i < n) p[i] = 0u;
}

// ====================== projection GEMM ======================
// C[M,2048] = A[M,K] @ W[2048,K]^T + bias   (A,W,C fp16; accum fp32)
template<int K>
__global__ __launch_bounds__(256) void k_proj(const f16* __restrict__ A,
                                              const f16* __restrict__ W,
                                              const float* __restrict__ bias,
                                              f16* __restrict__ C) {
  constexpr int PITCH = 40;
  __shared__ f16 lA[128 * PITCH];
  __shared__ f16 lB[128 * PITCH];
  const int m0 = blockIdx.x * 128;
  const int n0 = blockIdx.y * 128;
  const int tid  = threadIdx.x;
  const int lane = tid & 63;
  const int wave = tid >> 6;
  const int wm = (wave & 1) * 64;
  const int wn = (wave >> 1) * 64;
  const int ln = lane & 15;
  const int quad = lane >> 4;
  const int r  = tid >> 1;
  const int ce = (tid & 1) * 16;

  f32x4 acc[4][4] = {};

  for (int kb = 0; kb < K; kb += 32) {
    const f16* ga = A + (size_t)(m0 + r) * K + kb + ce;
    const f16* gb = W + (size_t)(n0 + r) * K + kb + ce;
    u32x4 a0 = *(const u32x4*)ga;
    u32x4 a1 = *(const u32x4*)(ga + 8);
    u32x4 b0 = *(const u32x4*)gb;
    u32x4 b1 = *(const u32x4*)(gb + 8);
    __syncthreads();
    *(u32x4*)&lA[r * PITCH + ce]     = a0;
    *(u32x4*)&lA[r * PITCH + ce + 8] = a1;
    *(u32x4*)&lB[r * PITCH + ce]     = b0;
    *(u32x4*)&lB[r * PITCH + ce + 8] = b1;
    __syncthreads();
    f16x8 af[4], bf[4];
#pragma unroll
    for (int i = 0; i < 4; i++) {
      af[i] = *(const f16x8*)&lA[(wm + i * 16 + ln) * PITCH + quad * 8];
      bf[i] = *(const f16x8*)&lB[(wn + i * 16 + ln) * PITCH + quad * 8];
    }
#pragma unroll
    for (int mi = 0; mi < 4; mi++)
#pragma unroll
      for (int ni = 0; ni < 4; ni++)
        acc[mi][ni] = __builtin_amdgcn_mfma_f32_16x16x32_f16(af[mi], bf[ni], acc[mi][ni], 0, 0, 0);
  }

#pragma unroll
  for (int ni = 0; ni < 4; ni++) {
    const int n = n0 + wn + ni * 16 + ln;
    const float bv = bias[n];
#pragma unroll
    for (int mi = 0; mi < 4; mi++) {
#pragma unroll
      for (int rr = 0; rr < 4; rr++) {
        const int m = m0 + wm + mi * 16 + quad * 4 + rr;
        C[(size_t)m * G4 + n] = (f16)(acc[mi][ni][rr] + bv);
      }
    }
  }
}

// ====================== persistent recurrent kernel (one chunk of T steps) ======================
// R8: XCD-local DATA path, verified with a negative control; flag protocol stays the proven
// R6 agent/MALL one in BOTH modes (liveness can never depend on the placement verdict).
//
//  - Verify: WG publishes (epoch<<8)|XCC_ID. Group LOCAL iff its 16 entries are uniform AND a
//    control row of 16 consecutive blockIdx is NON-uniform (catches degenerate/garbage readings —
//    the suspected R7 hang: uniform reading -> false LOCAL -> plain flags invisible -> livelock).
//  - LOCAL: producer h-stores plain (write-through to shared XCD L2; fast drain), consumer
//    bulk-loads h once with sc0 (bypass L1, hit XCD L2 ~90ns). No polling on data.
//  - Flags: relaxed agent atomics (MALL) always, exactly R6.
//  - Worst-case false verdict = stale data (absmax fail), never a hang.
__global__ __launch_bounds__(512, 2) void k_recur(
    const f16* __restrict__ Whh,      // [2048, 512] fp16
    const f16* __restrict__ xw,       // [T*256, 2048] fp16 (bias included)
    f16* __restrict__ ring,           // [4, 256, 512] f16
    int* __restrict__ flags,          // [256] per-(bi,gi) step counters (persist across chunks)
    int* __restrict__ xccbuf,         // [256] xcc publish slots
    f16* __restrict__ hclean,         // [T,256,512] (cleanAll) or [256,512] (last step only)
    float* __restrict__ cbuf,         // [256, 512] fp32 (carried across chunks)
    int t0, int T, int cleanAll, int epoch) {
  const int tid  = threadIdx.x;
  const int lane = tid & 63;
  const int wave = tid >> 6;        // 0..7
  const int gi = blockIdx.x >> 4;
  const int bi = blockIdx.x & 15;
  const int ln = lane & 15;
  const int quad = lane >> 4;

  __shared__ f16  lh[16 * 520];     // h-tile [16 rows][512] pitch 520
  __shared__ float lgate[16 * 132]; // gates [16 b][128] fp32, pitch 132

  // --- W_hh fragments -> registers (once); asm launder prevents sinking into the loop ---
  const int grow = (wave >> 1) * HD + gi * 32 + (wave & 1) * 16 + ln;
  f16x8 wf[16];
#pragma unroll
  for (int ks = 0; ks < 16; ks++) {
    u32x4 t = *(const u32x4*)(Whh + (size_t)grow * HD + ks * 32 + quad * 8);
    asm volatile("" : "+v"(t));
    wf[ks] = __builtin_bit_cast(f16x8, t);
  }

  // --- XCD-placement verification (per dispatch, negative-controlled) ---
  // HW_REG_XCC_ID = id 20; getreg imm = (size-1)<<11 | offset<<6 | id, size=32 offset=0.
  const uint32_t myxcc = __builtin_amdgcn_s_getreg((31u << 11) | 20u) & 0xffu;
  if (tid == 0)
    __hip_atomic_store(xccbuf + blockIdx.x, (epoch << 8) | (int)myxcc,
                       __ATOMIC_RELAXED, __HIP_MEMORY_SCOPE_AGENT);
  bool local;
  {
    // lanes 0..15: my group's entries (blockIdx = k*16 + bi, k=0..15)
    // lanes 16..31: control row (blockIdx = gi*16 + k) — 16 consecutive ids, must span XCDs
    // lanes 32..63: own slot (always becomes current)
    int slot = (lane < 16) ? (lane * 16 + bi)
             : (lane < 32) ? (gi * 16 + (lane - 16))
             : (int)blockIdx.x;
    const int* xp = xccbuf + slot;
    int e = __hip_atomic_load(xp, __ATOMIC_RELAXED, __HIP_MEMORY_SCOPE_AGENT);
    while (!__all((e >> 8) == epoch)) {
      __builtin_amdgcn_s_sleep(1);
      e = __hip_atomic_load(xp, __ATOMIC_RELAXED, __HIP_MEMORY_SCOPE_AGENT);
    }
    const int x = e & 0xff;
    const int g0 = __shfl(x, 0);
    const bool groupUni = __all(lane >= 16 || x == g0);
    const int c0 = __shfl(x, 16);
    const bool ctrlUni  = __all(lane < 16 || lane >= 32 || x == c0);
    local = groupUni && !ctrlUni;
  }

  // --- per-thread state: one (b,hl): b=tid>>5 (0..15), hl=tid&31 ---
  const int b_  = tid >> 5;
  const int hl_ = tid & 31;
  float cv = 0.f;
  if (t0 != 0) cv = cbuf[(size_t)(bi * 16 + b_) * HD + gi * 32 + hl_];

  const int* fl = flags + bi * 16;
  int* myflag = flags + bi * 16 + gi;
  uint64_t* lh64 = (uint64_t*)lh;

  for (int tt = 0; tt < T; tt++) {
    const int t = t0 + tt;

    // xw prefetch (independent of h) — issue first, lives across the poll
    const f16* xwp = xw + (size_t)(tt * 256 + bi * 16 + b_) * G4 + gi * 32 + hl_;
    float xg0 = (float)xwp[0];
    float xg1 = (float)xwp[512];
    float xg2 = (float)xwp[1024];
    float xg3 = (float)xwp[1536];

    // ---- poll the 16 producer flags (agent/MALL, proven R6 code, BOTH modes) ----
    {
      int v = __hip_atomic_load(fl + (lane & 15), __ATOMIC_RELAXED, __HIP_MEMORY_SCOPE_AGENT);
      while (!__all(v >= t)) {
        __builtin_amdgcn_s_sleep(1);
        v = __hip_atomic_load(fl + (lane & 15), __ATOMIC_RELAXED, __HIP_MEMORY_SCOPE_AGENT);
      }
    }
    asm volatile("" ::: "memory");   // keep data loads below the poll

    // ---- bulk-load h slot t ONCE: 4 coalesced u64/thread ----
    const uint64_t* hin64 = (const uint64_t*)(ring + (size_t)(t & 3) * (BATCH * HD)
                                              + (size_t)(bi * 16) * HD);
    uint64_t d[4];
    if (local) {
      const uint64_t* a0 = hin64 + tid;
      asm volatile(
          "global_load_dwordx2 %0, %4, off sc0\n\t"
          "global_load_dwordx2 %1, %5, off sc0\n\t"
          "global_load_dwordx2 %2, %6, off sc0\n\t"
          "global_load_dwordx2 %3, %7, off sc0\n\t"
          "s_waitcnt vmcnt(0)"
          : "=&v"(d[0]), "=&v"(d[1]), "=&v"(d[2]), "=&v"(d[3])
          : "v"(a0), "v"(a0 + 512), "v"(a0 + 1024), "v"(a0 + 1536)
          : "memory");
    } else {
#pragma unroll
      for (int j = 0; j < 4; j++)
        d[j] = __hip_atomic_load(hin64 + j * 512 + tid, __ATOMIC_RELAXED,
                                 __HIP_MEMORY_SCOPE_AGENT);
    }
#pragma unroll
    for (int j = 0; j < 4; j++) {
      const int e   = j * 512 + tid;
      const int row = e >> 7;
      const int c8  = e & 127;
      lh64[row * 130 + c8] = d[j];
    }
    __syncthreads();   // staging complete

    // ---- h @ Whh^T : each wave 16 gate-cols ----
    f32x4 acc = {0.f, 0.f, 0.f, 0.f};
#pragma unroll
    for (int ks = 0; ks < 16; ks++) {
      f16x8 af = *(const f16x8*)&lh[ln * 520 + ks * 32 + quad * 8];
      acc = __builtin_amdgcn_mfma_f32_16x16x32_f16(af, wf[ks], acc, 0, 0, 0);
    }
    const int gcol = (wave >> 1) * 32 + (wave & 1) * 16 + ln;
#pragma unroll
    for (int rr = 0; rr < 4; rr++)
      lgate[(quad * 4 + rr) * 132 + gcol] = acc[rr];
    __syncthreads();   // gates complete

    // ---- elementwise LSTM update: one (b,hl) per thread ----
    {
      float gi_ = lgate[b_ * 132 + 0  + hl_] + xg0;
      float gf_ = lgate[b_ * 132 + 32 + hl_] + xg1;
      float gg_ = lgate[b_ * 132 + 64 + hl_] + xg2;
      float go_ = lgate[b_ * 132 + 96 + hl_] + xg3;
      const float ig = 1.f / (1.f + expf(-gi_));
      const float fg = 1.f / (1.f + expf(-gf_));
      const float gg = gg_ > 0.f ? gg_ : expm1f(gg_);
      const float og = 1.f / (1.f + expf(-go_));
      cv = fg * cv + ig * gg;
      const float hv = og * (cv > 0.f ? cv : expm1f(cv));
      f16 hv16 = (f16)hv;
      unsigned short us;
      __builtin_memcpy(&us, &hv16, 2);
      const size_t col = (size_t)(bi * 16 + b_) * HD + gi * 32 + hl_;
      unsigned short* rp = (unsigned short*)(ring + (size_t)((t + 1) & 3) * (BATCH * HD) + col);
      if (local) *rp = us;   // plain write-through -> shared XCD L2 (fast drain)
      else __hip_atomic_store(rp, us, __ATOMIC_RELAXED, __HIP_MEMORY_SCOPE_AGENT);
      if (cleanAll)
        hclean[(size_t)(tt * 256 + bi * 16 + b_) * HD + gi * 32 + hl_] = hv16;
      else if (tt == T - 1)
        hclean[(size_t)(bi * 16 + b_) * HD + gi * 32 + hl_] = hv16;
    }
    __syncthreads();   // drains every wave's vmcnt -> data stores complete before flag
    if (tid == 0)
      __hip_atomic_store(myflag, t + 1, __ATOMIC_RELAXED, __HIP_MEMORY_SCOPE_AGENT);
  }

  // save c state for next chunk
  cbuf[(size_t)(bi * 16 + b_) * HD + gi * 32 + hl_] = cv;
}

// ====================== final FC: y[b] = h_last[b,:] . fc_w + fc_b ======================
__global__ __launch_bounds__(64) void k_fc(const f16* __restrict__ hlast,
                                           const float* __restrict__ fcw,
                                           const float* __restrict__ fcb,
                                           float* __restrict__ out) {
  const int b = blockIdx.x, lane = threadIdx.x;
  const f16* hp = hlast + (size_t)b * HD + lane * 8;
  float s = 0.f;
#pragma unroll
  for (int j = 0; j < 8; j++) s += (float)hp[j] * fcw[lane * 8 + j];
  for (int off = 32; off; off >>= 1) s += __shfl_down(s, off);
  if (lane == 0) out[b] = s + fcb[0];
}

// ============================ host ============================
extern "C" void kernel_launch(void* const* d_in, const int* in_sizes, int n_in,
                              void* d_out, int out_size, void* d_ws, size_t ws_size,
                              hipStream_t stream) {
  (void)in_sizes; (void)n_in; (void)out_size;
  const float* x      = (const float*)d_in[0];
  const float* wih[3] = {(const float*)d_in[1], (const float*)d_in[4], (const float*)d_in[7]};
  const float* whh[3] = {(const float*)d_in[2], (const float*)d_in[5], (const float*)d_in[8]};
  const float* bia[3] = {(const float*)d_in[3], (const float*)d_in[6], (const float*)d_in[9]};
  const float* fcw = (const float*)d_in[10];
  const float* fcb = (const float*)d_in[11];
  float* out = (float*)d_out;

  char* ws = (char*)d_ws;
  size_t off = 0;
  auto alloc = [&](size_t bytes) -> char* {
    off = (off + 255) & ~(size_t)255;
    char* p = ws + off;
    off += bytes;
    return p;
  };

  // ---- fixed allocations ----
  f16* xin = (f16*)alloc((size_t)S_LEN * BATCH * NIN * 2);
  f16* wih16[3];
  wih16[0] = (f16*)alloc((size_t)G4 * NIN * 2);
  wih16[1] = (f16*)alloc((size_t)G4 * HD * 2);
  wih16[2] = (f16*)alloc((size_t)G4 * HD * 2);
  f16* whh16[3];
  for (int l = 0; l < 3; l++) whh16[l] = (f16*)alloc((size_t)G4 * HD * 2);
  float* cbuf[3];
  for (int l = 0; l < 3; l++) cbuf[l] = (float*)alloc((size_t)BATCH * HD * 4);
  f16* ring[3];
  for (int l = 0; l < 3; l++) ring[l] = (f16*)alloc((size_t)4 * BATCH * HD * 2);
  int* flags = (int*)alloc(3 * 256 * 4);
  int* xccbuf = (int*)alloc(256 * 4);
  f16* hclean2 = (f16*)alloc((size_t)BATCH * HD * 2);

  // ---- adaptive chunk length T ----
  int T = 64;
  while (T > 4) {
    size_t need = off + 8 * 256
                + 2 * ((size_t)T * BATCH * HD * 2 + 256)   // hclean0, hclean1
                + (size_t)T * BATCH * G4 * 2;              // xw
    if (need <= ws_size) break;
    T >>= 1;
  }
  f16* hclean01[2];
  hclean01[0] = (f16*)alloc((size_t)T * BATCH * HD * 2);
  hclean01[1] = (f16*)alloc((size_t)T * BATCH * HD * 2);
  f16* xw = (f16*)alloc((size_t)T * BATCH * G4 * 2);

  // ---- prep ----
  {
    int n = S_LEN * BATCH * NIN;
    k_x_transpose<<<dim3(n / 256), dim3(256), 0, stream>>>(x, xin);
  }
  k_f32_to_f16<<<dim3((G4 * NIN + 255) / 256), dim3(256), 0, stream>>>(wih[0], wih16[0], G4 * NIN);
  k_f32_to_f16<<<dim3((G4 * HD + 255) / 256), dim3(256), 0, stream>>>(wih[1], wih16[1], G4 * HD);
  k_f32_to_f16<<<dim3((G4 * HD + 255) / 256), dim3(256), 0, stream>>>(wih[2], wih16[2], G4 * HD);
  for (int l = 0; l < 3; l++)
    k_f32_to_f16<<<dim3((G4 * HD + 255) / 256), dim3(256), 0, stream>>>(whh[l], whh16[l], G4 * HD);
  // zero ring slot 0 (h_{-1}=0) of each layer + flags + xccbuf (contiguous)
  for (int l = 0; l < 3; l++)
    k_zero_i32<<<dim3(BATCH * HD / 2 / 256), dim3(256), 0, stream>>>((uint32_t*)ring[l],
                                                                     BATCH * HD / 2);
  k_zero_i32<<<dim3(4), dim3(256), 0, stream>>>((uint32_t*)flags, 3 * 256 + 256);

  // ---- chunk-interleaved layers ----
  int chunkIdx = 0;
  for (int t0 = 0; t0 < S_LEN; t0 += T, chunkIdx++) {
    for (int l = 0; l < 3; l++) {
      dim3 pg(T * BATCH / 128, G4 / 128);
      if (l == 0) {
        const f16* Achunk = xin + (size_t)t0 * BATCH * NIN;
        k_proj<NIN><<<pg, dim3(256), 0, stream>>>(Achunk, wih16[0], bia[0], xw);
      } else {
        k_proj<HD><<<pg, dim3(256), 0, stream>>>(hclean01[l - 1], wih16[l], bia[l], xw);
      }
      f16* hc = (l == 2) ? hclean2 : hclean01[l];
      const int epoch = 1 + chunkIdx * 3 + l;
      k_recur<<<dim3(256), dim3(512), 0, stream>>>(whh16[l], xw, ring[l], flags + l * 256,
                                                   xccbuf, hc, cbuf[l], t0, T, l != 2, epoch);
    }
  }

  // ---- final FC ----
  k_fc<<<dim3(BATCH), dim3(64), 0, stream>>>(hclean2, fcw, fcb, out);
}